// Round 1
// baseline (128.397 us; speedup 1.0000x reference)
//
#include <hip/hip_runtime.h>
#include <hip/hip_bf16.h>

// Flash attention fwd, bf16 MFMA, fp32 accum. BH=32, S=2048, D=64, B=2 masks.
// Block = 512 thr (8 waves), each block: one head x 256 q rows; wave: 32 q rows.
// KV tiles of 64 keys; K [64][64] + V^T [64][64] bf16 in LDS, XOR-swizzled.
// P routed through per-wave LDS (32x64 bf16). T14 async staging (load-early/
// write-late). Online softmax, wave-parallel via shfl_xor over 16-lane groups.

#define SQ 2048
#define DD 64
#define NT 32   // 2048 / 64 KV tiles

typedef __attribute__((ext_vector_type(8))) short bf16x8;
typedef __attribute__((ext_vector_type(4))) float f32x4;

__device__ __forceinline__ short f2bf(float x) {
    union { float f; unsigned u; } a; a.f = x;
    unsigned r = a.u + 0x7fffu + ((a.u >> 16) & 1u);   // RNE, finite inputs
    return (short)(r >> 16);
}

__device__ __forceinline__ int swz(int row, int colByte) {
    // 128-byte rows; spread 16B column slots across banks per 8-row stripe
    return row * 128 + (colByte ^ ((row & 7) << 4));
}

__global__ __launch_bounds__(512, 2) void attn_fwd(
    const float* __restrict__ q, const float* __restrict__ k,
    const float* __restrict__ v, const int* __restrict__ masks,
    float* __restrict__ out)
{
    __shared__ alignas(16) char smem[49152];  // K 8K | Vt 8K | P 8x4K

    const int x = blockIdx.x;
    // bijective XCD swizzle: head's 8 q-blocks land on one XCD (L2 K/V reuse)
    const int h  = (x & 7) + 8 * ((x >> 3) >> 3);
    const int qb = (x >> 3) & 7;
    const int b  = h & 1;                 // masks row: bh % 2
    const int tid  = threadIdx.x;
    const int w    = tid >> 6;
    const int lane = tid & 63;
    const int l15  = lane & 15;
    const int l4   = lane >> 4;

    const float* __restrict__ qh = q + (size_t)h * SQ * DD;
    const float* __restrict__ kh = k + (size_t)h * SQ * DD;
    const float* __restrict__ vh = v + (size_t)h * SQ * DD;
    const int*   __restrict__ mrow = masks + b * SQ;

    char* Kb = smem;             // K tile  [key][d] bf16, swizzled
    char* Vb = smem + 8192;      // V^T tile [d][key] bf16, swizzled
    char* Pl = smem + 16384 + w * 4096;   // per-wave P [32 q][64 key]

    // ---- Q fragments, scaled by 0.125 (exact) ----
    const int q0 = qb * 256 + w * 32;
    bf16x8 qf[2][2];
#pragma unroll
    for (int t = 0; t < 2; ++t)
#pragma unroll
      for (int dc = 0; dc < 2; ++dc) {
        const float* p = qh + (size_t)(q0 + t * 16 + l15) * DD + dc * 32 + l4 * 8;
        float4 a = *(const float4*)p;
        float4 c4 = *(const float4*)(p + 4);
        bf16x8 f;
        f[0] = f2bf(a.x * 0.125f);  f[1] = f2bf(a.y * 0.125f);
        f[2] = f2bf(a.z * 0.125f);  f[3] = f2bf(a.w * 0.125f);
        f[4] = f2bf(c4.x * 0.125f); f[5] = f2bf(c4.y * 0.125f);
        f[6] = f2bf(c4.z * 0.125f); f[7] = f2bf(c4.w * 0.125f);
        qf[t][dc] = f;
      }

    const f32x4 fzero = {0.f, 0.f, 0.f, 0.f};
    f32x4 o[2][4];
    float m_r[2][4], l_r[2][4];
#pragma unroll
    for (int t = 0; t < 2; ++t) {
#pragma unroll
      for (int dt = 0; dt < 4; ++dt) o[t][dt] = fzero;
#pragma unroll
      for (int r = 0; r < 4; ++r) { m_r[t][r] = -1e30f; l_r[t][r] = 0.f; }
    }

    // staging assignments
    const int kkK = tid >> 3, d0K = (tid & 7) * 8;   // K: row kkK, d d0K..+7
    const int kkV = tid & 63, d0V = (tid >> 6) * 8;  // V: row kkV, d d0V..+7
    const int koff = swz(kkK, 2 * d0K);              // one ds_write_b128

    // ---- prologue: stage tile 0 ----
    {
        const float* kp = kh + (size_t)kkK * DD + d0K;
        const float* vp = vh + (size_t)kkV * DD + d0V;
        float4 ka = *(const float4*)kp, kb2 = *(const float4*)(kp + 4);
        float4 va = *(const float4*)vp, vb2 = *(const float4*)(vp + 4);
        bf16x8 kw;
        kw[0]=f2bf(ka.x); kw[1]=f2bf(ka.y); kw[2]=f2bf(ka.z); kw[3]=f2bf(ka.w);
        kw[4]=f2bf(kb2.x); kw[5]=f2bf(kb2.y); kw[6]=f2bf(kb2.z); kw[7]=f2bf(kb2.w);
        *(bf16x8*)(Kb + koff) = kw;
        float vv[8] = {va.x, va.y, va.z, va.w, vb2.x, vb2.y, vb2.z, vb2.w};
#pragma unroll
        for (int j = 0; j < 8; ++j)   // row = d0V+j, (row&7)==j
            *(short*)(Vb + (d0V + j) * 128 + ((2 * kkV) ^ (j << 4))) = f2bf(vv[j]);
    }
    __syncthreads();

    for (int it = 0; it < NT; ++it) {
        const int kt = it * 64;
        const bool more = (it + 1 < NT);
        float4 ka, kb2, va, vb2;
        if (more) {   // T14: issue next-tile loads early, write after barrier
            const float* kp = kh + (size_t)(kt + 64 + kkK) * DD + d0K;
            const float* vp = vh + (size_t)(kt + 64 + kkV) * DD + d0V;
            ka = *(const float4*)kp;  kb2 = *(const float4*)(kp + 4);
            va = *(const float4*)vp;  vb2 = *(const float4*)(vp + 4);
        }
        int mi[4];
#pragma unroll
        for (int c = 0; c < 4; ++c) mi[c] = mrow[kt + c * 16 + l15];

        // K fragments: B-operand = K[key][d], 16B contiguous, swizzle-free banks
        bf16x8 kf[4][2];
#pragma unroll
        for (int c = 0; c < 4; ++c)
#pragma unroll
          for (int dc = 0; dc < 2; ++dc)
            kf[c][dc] = *(const bf16x8*)(Kb + swz(c * 16 + l15, 2 * (dc * 32 + l4 * 8)));

#pragma unroll
        for (int t = 0; t < 2; ++t) {
            f32x4 s[4];
#pragma unroll
            for (int c = 0; c < 4; ++c) {
                s[c] = fzero;
                s[c] = __builtin_amdgcn_mfma_f32_16x16x32_bf16(qf[t][0], kf[c][0], s[c], 0, 0, 0);
                s[c] = __builtin_amdgcn_mfma_f32_16x16x32_bf16(qf[t][1], kf[c][1], s[c], 0, 0, 0);
            }
            // online softmax, rows r of this 16-row subtile (C layout:
            // row = 4*(lane>>4)+r, col = c*16 + (lane&15))
#pragma unroll
            for (int r = 0; r < 4; ++r) {
                float sv[4];
#pragma unroll
                for (int c = 0; c < 4; ++c) sv[c] = mi[c] ? -1e30f : s[c][r];
                float mx = fmaxf(fmaxf(sv[0], sv[1]), fmaxf(sv[2], sv[3]));
#pragma unroll
                for (int dd = 1; dd < 16; dd <<= 1) mx = fmaxf(mx, __shfl_xor(mx, dd));
                const float mn = fmaxf(m_r[t][r], mx);
                const float al = __expf(m_r[t][r] - mn);
                m_r[t][r] = mn;
                float ps = 0.f, pv[4];
#pragma unroll
                for (int c = 0; c < 4; ++c) {
                    pv[c] = mi[c] ? 0.f : __expf(s[c][r] - mn);  // masked => exactly 0
                    ps += pv[c];
                }
#pragma unroll
                for (int dd = 1; dd < 16; dd <<= 1) ps += __shfl_xor(ps, dd);
                l_r[t][r] = l_r[t][r] * al + ps;
#pragma unroll
                for (int dt = 0; dt < 4; ++dt) o[t][dt][r] *= al;
                const int row = t * 16 + l4 * 4 + r;
#pragma unroll
                for (int c = 0; c < 4; ++c)
                    *(short*)(Pl + row * 128 + ((2 * (c * 16 + l15)) ^ ((row & 7) << 4)))
                        = f2bf(pv[c]);
            }
        }

        // V^T fragments: B-operand = V[key][d] read via Vt[d][key]
        bf16x8 vf[4][2];
#pragma unroll
        for (int dt = 0; dt < 4; ++dt)
#pragma unroll
          for (int kc = 0; kc < 2; ++kc)
            vf[dt][kc] = *(const bf16x8*)(Vb + swz(dt * 16 + l15, 2 * (kc * 32 + l4 * 8)));

        // P fragments: A-operand rows = q, contiguous keys (same-wave DS ordering
        // guarantees write->read; P region is wave-private, no barrier)
        bf16x8 pf[2][2];
#pragma unroll
        for (int t = 0; t < 2; ++t)
#pragma unroll
          for (int kc = 0; kc < 2; ++kc)
            pf[t][kc] = *(const bf16x8*)(Pl + swz(t * 16 + l15, 2 * (kc * 32 + l4 * 8)));

#pragma unroll
        for (int t = 0; t < 2; ++t)
#pragma unroll
          for (int dt = 0; dt < 4; ++dt) {
            o[t][dt] = __builtin_amdgcn_mfma_f32_16x16x32_bf16(pf[t][0], vf[dt][0], o[t][dt], 0, 0, 0);
            o[t][dt] = __builtin_amdgcn_mfma_f32_16x16x32_bf16(pf[t][1], vf[dt][1], o[t][dt], 0, 0, 0);
          }

        __syncthreads();          // all reads of K/Vt done
        if (more) {
            bf16x8 kw;
            kw[0]=f2bf(ka.x); kw[1]=f2bf(ka.y); kw[2]=f2bf(ka.z); kw[3]=f2bf(ka.w);
            kw[4]=f2bf(kb2.x); kw[5]=f2bf(kb2.y); kw[6]=f2bf(kb2.z); kw[7]=f2bf(kb2.w);
            *(bf16x8*)(Kb + koff) = kw;
            float vv[8] = {va.x, va.y, va.z, va.w, vb2.x, vb2.y, vb2.z, vb2.w};
#pragma unroll
            for (int j = 0; j < 8; ++j)
                *(short*)(Vb + (d0V + j) * 128 + ((2 * kkV) ^ (j << 4))) = f2bf(vv[j]);
        }
        __syncthreads();          // next tile visible
    }

    // ---- epilogue: O / l ----
#pragma unroll
    for (int t = 0; t < 2; ++t) {
        float inv[4];
#pragma unroll
        for (int r = 0; r < 4; ++r) inv[r] = 1.0f / l_r[t][r];
#pragma unroll
        for (int dt = 0; dt < 4; ++dt)
#pragma unroll
          for (int r = 0; r < 4; ++r) {
            const int row = q0 + t * 16 + l4 * 4 + r;
            out[(size_t)h * SQ * DD + (size_t)row * DD + dt * 16 + l15]
                = o[t][dt][r] * inv[r];
          }
    }
}

extern "C" void kernel_launch(void* const* d_in, const int* in_sizes, int n_in,
                              void* d_out, int out_size, void* d_ws, size_t ws_size,
                              hipStream_t stream) {
    const float* q = (const float*)d_in[0];
    const float* k = (const float*)d_in[1];
    const float* v = (const float*)d_in[2];
    const int* masks = (const int*)d_in[3];
    float* out = (float*)d_out;
    attn_fwd<<<dim3(256), dim3(512), 0, stream>>>(q, k, v, masks, out);
}

// Round 2
// 76.031 us; speedup vs baseline: 1.6887x; 1.6887x over previous
//
#include <hip/hip_runtime.h>
#include <hip/hip_bf16.h>

// Flash attention fwd, swapped-QK^T 32x32x16 MFMA, in-register softmax.
// BH=32, S=2048, D=64, B=2 key-padding masks.
// Block = 256 thr (4 waves), each wave 32 q rows; grid 512 (2 blocks/CU).
// S^T = mfma(K, Q): lane owns q = lane&31 -> softmax is in-lane + 1 shfl_xor(32).
// P kept in registers (cvt_pk bf16 + xor32 exchange) -> PV: O^T = mfma(V^T, P^T).
// Mask staged once as log2e-scaled addend, used as MFMA C-init.
// T13 defer-rescale (8 nats). T14 load-early/write-late staging. exp2 domain.

#define SQ 2048
#define DD 64
#define NT 32   // 2048 / 64 KV tiles

typedef __attribute__((ext_vector_type(8)))  short bf16x8;
typedef __attribute__((ext_vector_type(16))) float f32x16;

#define LOG2E  1.4426950408889634f
#define QSCALE (0.125f * LOG2E)
#define MASKV  (-4294967295.0f * LOG2E)   // MASK_NUM in log2 domain
#define THRL   (8.0f * LOG2E)             // defer-rescale threshold

__device__ __forceinline__ short f2bf(float x) {
    union { float f; unsigned u; } a; a.f = x;
    unsigned r = a.u + 0x7fffu + ((a.u >> 16) & 1u);   // RNE, finite inputs
    return (short)(r >> 16);
}
__device__ __forceinline__ int cvt_pk(float lo, float hi) {
    int r;
    asm("v_cvt_pk_bf16_f32 %0, %1, %2" : "=v"(r) : "v"(lo), "v"(hi));
    return r;
}
__device__ __forceinline__ int swz(int row, int colByte) {
    return row * 128 + (colByte ^ ((row & 7) << 4));
}

__global__ __launch_bounds__(256, 2) void attn_fwd(
    const float* __restrict__ q, const float* __restrict__ k,
    const float* __restrict__ v, const int* __restrict__ masks,
    float* __restrict__ out)
{
    __shared__ alignas(16) char smem[24576];  // K 8K | Vt 8K | maskf 8K
    char*  Kb = smem;                          // [64 key][64 d] bf16, swizzled
    char*  Vb = smem + 8192;                   // [64 d][64 key] bf16, swizzled
    float* Mf = (float*)(smem + 16384);        // mask addend [2048]

    const int x    = blockIdx.x;
    const int orig = (x & 7) * 64 + (x >> 3);  // bijective XCD swizzle (512=8*64)
    const int h    = orig >> 4;                // head: 4 heads/XCD -> K/V L2 reuse
    const int qb   = orig & 15;
    const int tid  = threadIdx.x;
    const int w    = tid >> 6;
    const int lane = tid & 63;
    const int l31  = lane & 31;
    const int hi   = lane >> 5;

    const float* __restrict__ qh = q + (size_t)h * SQ * DD;
    const float* __restrict__ kh = k + (size_t)h * SQ * DD;
    const float* __restrict__ vh = v + (size_t)h * SQ * DD;
    const int*   __restrict__ mrow = masks + (h & 1) * SQ;   // bh % 2

    // ---- stage mask addend table once (2048 floats) ----
    {
        int4 a = *(const int4*)(mrow + tid * 8);
        int4 b = *(const int4*)(mrow + tid * 8 + 4);
        float4 fa = { a.x ? MASKV : 0.f, a.y ? MASKV : 0.f,
                      a.z ? MASKV : 0.f, a.w ? MASKV : 0.f };
        float4 fb = { b.x ? MASKV : 0.f, b.y ? MASKV : 0.f,
                      b.z ? MASKV : 0.f, b.w ? MASKV : 0.f };
        *(float4*)(Mf + tid * 8)     = fa;
        *(float4*)(Mf + tid * 8 + 4) = fb;
    }

    // ---- Q fragments (B-operand: col=q=l31, k=d chunk), log2e*0.125 scale ----
    const int qrow = qb * 128 + w * 32 + l31;
    bf16x8 qf[4];
#pragma unroll
    for (int dc = 0; dc < 4; ++dc) {
        const float* p = qh + (size_t)qrow * DD + dc * 16 + hi * 8;
        float4 a = *(const float4*)p;
        float4 b = *(const float4*)(p + 4);
        bf16x8 f;
        f[0] = f2bf(a.x * QSCALE); f[1] = f2bf(a.y * QSCALE);
        f[2] = f2bf(a.z * QSCALE); f[3] = f2bf(a.w * QSCALE);
        f[4] = f2bf(b.x * QSCALE); f[5] = f2bf(b.y * QSCALE);
        f[6] = f2bf(b.z * QSCALE); f[7] = f2bf(b.w * QSCALE);
        qf[dc] = f;
    }

    f32x16 o[2];
#pragma unroll
    for (int dt = 0; dt < 2; ++dt)
#pragma unroll
      for (int i = 0; i < 16; ++i) o[dt][i] = 0.f;
    float m = -3.0e38f, l = 0.f;

    // staging slots (256 threads): K rows {rK, rK+32} x d-chunk cK; V key kV x d {dV, dV+32}
    const int rK = tid >> 3, cK = tid & 7;
    const int kV = tid & 63, dV = (tid >> 6) * 8;

    float4 kA0, kA1, kB0, kB1, vA0, vA1, vB0, vB1;
#define LOADKV(kt)                                                        \
    {   const float* kpA = kh + (size_t)((kt) + rK)      * DD + 8 * cK;  \
        const float* kpB = kh + (size_t)((kt) + rK + 32) * DD + 8 * cK;  \
        const float* vpA = vh + (size_t)((kt) + kV) * DD + dV;           \
        const float* vpB = vpA + 32;                                      \
        kA0 = *(const float4*)kpA; kA1 = *(const float4*)(kpA + 4);      \
        kB0 = *(const float4*)kpB; kB1 = *(const float4*)(kpB + 4);      \
        vA0 = *(const float4*)vpA; vA1 = *(const float4*)(vpA + 4);      \
        vB0 = *(const float4*)vpB; vB1 = *(const float4*)(vpB + 4);      }

#define WRITEKV()                                                         \
    {   bf16x8 kw;                                                        \
        kw[0]=f2bf(kA0.x); kw[1]=f2bf(kA0.y); kw[2]=f2bf(kA0.z); kw[3]=f2bf(kA0.w); \
        kw[4]=f2bf(kA1.x); kw[5]=f2bf(kA1.y); kw[6]=f2bf(kA1.z); kw[7]=f2bf(kA1.w); \
        *(bf16x8*)(Kb + swz(rK, 16 * cK)) = kw;                           \
        kw[0]=f2bf(kB0.x); kw[1]=f2bf(kB0.y); kw[2]=f2bf(kB0.z); kw[3]=f2bf(kB0.w); \
        kw[4]=f2bf(kB1.x); kw[5]=f2bf(kB1.y); kw[6]=f2bf(kB1.z); kw[7]=f2bf(kB1.w); \
        *(bf16x8*)(Kb + swz(rK + 32, 16 * cK)) = kw;                      \
        float va[8] = {vA0.x, vA0.y, vA0.z, vA0.w, vA1.x, vA1.y, vA1.z, vA1.w}; \
        float vb[8] = {vB0.x, vB0.y, vB0.z, vB0.w, vB1.x, vB1.y, vB1.z, vB1.w}; \
        _Pragma("unroll")                                                 \
        for (int j = 0; j < 8; ++j) {                                     \
            *(short*)(Vb + (dV + j)      * 128 + ((2 * kV) ^ (j << 4))) = f2bf(va[j]); \
            *(short*)(Vb + (dV + 32 + j) * 128 + ((2 * kV) ^ (j << 4))) = f2bf(vb[j]); \
        }                                                                 }

    LOADKV(0)
    WRITEKV()
    __syncthreads();

    for (int it = 0; it < NT; ++it) {
        const int kt = it * 64;
        if (it + 1 < NT) LOADKV(kt + 64)      // T14: issue early, write late

        // ---- QK^T (swapped): s[kb] = S^T[32kb+key][q], C-init = mask addend ----
        const float* mf = Mf + kt;
        f32x16 s0, s1;
#pragma unroll
        for (int g = 0; g < 4; ++g) {
            float4 m0 = *(const float4*)(mf + 8 * g + 4 * hi);        // kb=0
            float4 m1 = *(const float4*)(mf + 32 + 8 * g + 4 * hi);   // kb=1
            s0[4*g+0] = m0.x; s0[4*g+1] = m0.y; s0[4*g+2] = m0.z; s0[4*g+3] = m0.w;
            s1[4*g+0] = m1.x; s1[4*g+1] = m1.y; s1[4*g+2] = m1.z; s1[4*g+3] = m1.w;
        }
#pragma unroll
        for (int dc = 0; dc < 4; ++dc) {
            bf16x8 k0 = *(const bf16x8*)(Kb + swz(l31,      32 * dc + 16 * hi));
            bf16x8 k1 = *(const bf16x8*)(Kb + swz(32 + l31, 32 * dc + 16 * hi));
            s0 = __builtin_amdgcn_mfma_f32_32x32x16_bf16(k0, qf[dc], s0, 0, 0, 0);
            s1 = __builtin_amdgcn_mfma_f32_32x32x16_bf16(k1, qf[dc], s1, 0, 0, 0);
        }

        // ---- in-lane max (pairwise tree) + cross-half combine ----
        float t[16];
#pragma unroll
        for (int i = 0; i < 16; ++i) t[i] = fmaxf(s0[i], s1[i]);
#pragma unroll
        for (int stp = 8; stp >= 1; stp >>= 1)
#pragma unroll
            for (int i = 0; i < stp; ++i) t[i] = fmaxf(t[i], t[i + stp]);
        float pmax = fmaxf(t[0], __shfl_xor(t[0], 32));

        float mn = m;
        if (!__all(pmax <= m + THRL)) {       // T13 defer-rescale
            mn = fmaxf(m, pmax);
            float al = __builtin_amdgcn_exp2f(m - mn);
            l *= al;
#pragma unroll
            for (int dt = 0; dt < 2; ++dt)
#pragma unroll
              for (int i = 0; i < 16; ++i) o[dt][i] *= al;
            m = mn;
        }

        float p0[16], p1[16];
        float ps0 = 0.f, ps1 = 0.f;
#pragma unroll
        for (int i = 0; i < 16; ++i) {
            p0[i] = __builtin_amdgcn_exp2f(s0[i] - mn); ps0 += p0[i];
            p1[i] = __builtin_amdgcn_exp2f(s1[i] - mn); ps1 += p1[i];
        }
        float ps = ps0 + ps1;
        l += ps + __shfl_xor(ps, 32);

        // ---- pack P -> bf16 pairs; exchange halves (keys 4hi..4hi+3 <-> other) ----
        int pk[2][4][2], sw[2][4][2];
#pragma unroll
        for (int g = 0; g < 4; ++g) {
            pk[0][g][0] = cvt_pk(p0[4*g+0], p0[4*g+1]);
            pk[0][g][1] = cvt_pk(p0[4*g+2], p0[4*g+3]);
            pk[1][g][0] = cvt_pk(p1[4*g+0], p1[4*g+1]);
            pk[1][g][1] = cvt_pk(p1[4*g+2], p1[4*g+3]);
        }
#pragma unroll
        for (int kb = 0; kb < 2; ++kb)
#pragma unroll
          for (int g = 0; g < 4; ++g)
#pragma unroll
            for (int j = 0; j < 2; ++j)
                sw[kb][g][j] = __shfl_xor(pk[kb][g][j], 32);

        // ---- PV: O^T += V^T . P^T ----
#pragma unroll
        for (int kc = 0; kc < 4; ++kc) {
            const int kb = kc >> 1, kp = kc & 1;
            union { int u[4]; bf16x8 b; } pu;
            pu.u[0] = hi ? sw[kb][2*kp+1][0] : pk[kb][2*kp][0];
            pu.u[1] = hi ? sw[kb][2*kp+1][1] : pk[kb][2*kp][1];
            pu.u[2] = hi ? pk[kb][2*kp+1][0] : sw[kb][2*kp][0];
            pu.u[3] = hi ? pk[kb][2*kp+1][1] : sw[kb][2*kp][1];
#pragma unroll
            for (int dt = 0; dt < 2; ++dt) {
                bf16x8 vf = *(const bf16x8*)(Vb + swz(32 * dt + l31, 32 * kc + 16 * hi));
                o[dt] = __builtin_amdgcn_mfma_f32_32x32x16_bf16(vf, pu.b, o[dt], 0, 0, 0);
            }
        }

        __syncthreads();          // K/Vt reads done
        if (it + 1 < NT) WRITEKV()
        __syncthreads();          // next tile visible
    }

    // ---- epilogue: O^T col q=l31, row d = (reg&3)+8*(reg>>2)+4*hi+32*dt ----
    const float invl = 1.0f / l;
    float* op = out + (size_t)h * SQ * DD + (size_t)qrow * DD;
#pragma unroll
    for (int dt = 0; dt < 2; ++dt)
#pragma unroll
      for (int g = 0; g < 4; ++g) {
        float4 r = { o[dt][4*g+0] * invl, o[dt][4*g+1] * invl,
                     o[dt][4*g+2] * invl, o[dt][4*g+3] * invl };
        *(float4*)(op + 32 * dt + 8 * g + 4 * hi) = r;
      }
}

extern "C" void kernel_launch(void* const* d_in, const int* in_sizes, int n_in,
                              void* d_out, int out_size, void* d_ws, size_t ws_size,
                              hipStream_t stream) {
    const float* q = (const float*)d_in[0];
    const float* k = (const float*)d_in[1];
    const float* v = (const float*)d_in[2];
    const int* masks = (const int*)d_in[3];
    float* out = (float*)d_out;
    attn_fwd<<<dim3(512), dim3(256), 0, stream>>>(q, k, v, masks, out);
}

// Round 4
// 62.648 us; speedup vs baseline: 2.0495x; 1.2136x over previous
//
#include <hip/hip_runtime.h>
#include <hip/hip_bf16.h>

// Flash attention fwd, swapped-QK^T 32x32x16 MFMA, in-register softmax.
// BH=32, S=2048, D=64, B=2 key-padding masks.
// Block = 256 thr (4 waves), wave = 32 q rows; grid 512 (2 blocks/CU).
// S^T = mfma(K, Q): lane owns q = lane&31; softmax in-lane + permlane32_swap.
// P in registers (cvt_pk bf16 + permlane32_swap) -> PV: O^T = mfma(V^T, P^T).
// permlane32_swap HW semantics: DST.row1 <-> SRC.row0, returns {vdst', vsrc'}:
//   r[0] = [a.row0 | b.row0-from-partner], r[1] = [a.row1-from-partner | b.row1].
// Mask staged once as log2e-scaled addend, used as MFMA C-init.
// K/V double-buffered in LDS (1 barrier/tile). All f32->bf16 via cvt_pk.
// T5 setprio around MFMA. T13 defer-rescale. T14 load-early/write-late. exp2.

#define SQ 2048
#define DD 64
#define NT 32   // 2048 / 64 KV tiles

typedef __attribute__((ext_vector_type(8)))  short bf16x8;
typedef __attribute__((ext_vector_type(16))) float f32x16;
typedef __attribute__((ext_vector_type(2)))  unsigned uint2v;

#define LOG2E  1.4426950408889634f
#define QSCALE (0.125f * LOG2E)
#define MASKV  (-4294967295.0f * LOG2E)   // MASK_NUM in log2 domain
#define THRL   (8.0f * LOG2E)             // defer-rescale threshold

__device__ __forceinline__ int cvt_pk(float lo, float hi) {
    int r;
    asm("v_cvt_pk_bf16_f32 %0, %1, %2" : "=v"(r) : "v"(lo), "v"(hi));
    return r;
}
__device__ __forceinline__ int swz(int row, int colByte) {
    return row * 128 + (colByte ^ ((row & 7) << 4));
}
// orientation-independent cross-half combines: swap(x,x) yields
// {row0-broadcast, row1-broadcast} in some order under either row-pairing.
__device__ __forceinline__ float xmax(float x) {
#if __has_builtin(__builtin_amdgcn_permlane32_swap)
    union { float f; unsigned u; } a; a.f = x;
    uint2v r = __builtin_amdgcn_permlane32_swap(a.u, a.u, false, false);
    union { unsigned u; float f; } p0, p1; p0.u = r[0]; p1.u = r[1];
    return fmaxf(p0.f, p1.f);
#else
    return fmaxf(x, __shfl_xor(x, 32));
#endif
}
__device__ __forceinline__ float xsum(float x) {
#if __has_builtin(__builtin_amdgcn_permlane32_swap)
    union { float f; unsigned u; } a; a.f = x;
    uint2v r = __builtin_amdgcn_permlane32_swap(a.u, a.u, false, false);
    union { unsigned u; float f; } p0, p1; p0.u = r[0]; p1.u = r[1];
    return p0.f + p1.f;
#else
    return x + __shfl_xor(x, 32);
#endif
}
// PV B-operand words from P packs: a = pk[2kp] (keys 16kp+4hi+0..3),
// b = pk[2kp+1] (keys 16kp+8+4hi+0..3).
// lo01 needs: hi=0 -> own a, hi=1 -> partner b.  => r[0]
// hi23 needs: hi=0 -> partner a, hi=1 -> own b.  => r[1]
__device__ __forceinline__ void plswap2(unsigned a, unsigned b,
                                        unsigned& lo01, unsigned& hi23, int hi) {
#if __has_builtin(__builtin_amdgcn_permlane32_swap)
    uint2v r = __builtin_amdgcn_permlane32_swap(a, b, false, false);
    lo01 = r[0]; hi23 = r[1];
#else
    unsigned pa = (unsigned)__shfl_xor((int)a, 32);
    unsigned pb = (unsigned)__shfl_xor((int)b, 32);
    lo01 = hi ? pb : a;
    hi23 = hi ? b : pa;
#endif
}

__global__ __launch_bounds__(256, 2) void attn_fwd(
    const float* __restrict__ q, const float* __restrict__ k,
    const float* __restrict__ v, const int* __restrict__ masks,
    float* __restrict__ out)
{
    // buf0: K@0 V@8192 | buf1: K@16384 V@24576 | mask @32768 (8KB)
    __shared__ alignas(16) char smem[40960];
    float* Mf = (float*)(smem + 32768);

    const int x    = blockIdx.x;
    const int orig = (x & 7) * 64 + (x >> 3);  // bijective XCD swizzle (512=8*64)
    const int h    = orig >> 4;                // 4 heads/XCD -> K/V L2 reuse
    const int qb   = orig & 15;
    const int tid  = threadIdx.x;
    const int w    = tid >> 6;
    const int lane = tid & 63;
    const int l31  = lane & 31;
    const int hi   = lane >> 5;

    const float* __restrict__ qh = q + (size_t)h * SQ * DD;
    const float* __restrict__ kh = k + (size_t)h * SQ * DD;
    const float* __restrict__ vh = v + (size_t)h * SQ * DD;
    const int*   __restrict__ mrow = masks + (h & 1) * SQ;   // bh % 2

    // ---- stage mask addend table once (2048 floats) ----
    {
        int4 a = *(const int4*)(mrow + tid * 8);
        int4 b = *(const int4*)(mrow + tid * 8 + 4);
        float4 fa = { a.x ? MASKV : 0.f, a.y ? MASKV : 0.f,
                      a.z ? MASKV : 0.f, a.w ? MASKV : 0.f };
        float4 fb = { b.x ? MASKV : 0.f, b.y ? MASKV : 0.f,
                      b.z ? MASKV : 0.f, b.w ? MASKV : 0.f };
        *(float4*)(Mf + tid * 8)     = fa;
        *(float4*)(Mf + tid * 8 + 4) = fb;
    }

    // ---- Q fragments (B-operand: col=q=l31, k=d chunk), log2e*0.125 scale ----
    const int qrow = qb * 128 + w * 32 + l31;
    bf16x8 qf[4];
#pragma unroll
    for (int dc = 0; dc < 4; ++dc) {
        const float* p = qh + (size_t)qrow * DD + dc * 16 + hi * 8;
        float4 a = *(const float4*)p;
        float4 b = *(const float4*)(p + 4);
        union { int i[4]; bf16x8 v; } f;
        f.i[0] = cvt_pk(a.x * QSCALE, a.y * QSCALE);
        f.i[1] = cvt_pk(a.z * QSCALE, a.w * QSCALE);
        f.i[2] = cvt_pk(b.x * QSCALE, b.y * QSCALE);
        f.i[3] = cvt_pk(b.z * QSCALE, b.w * QSCALE);
        qf[dc] = f.v;
    }

    f32x16 o[2];
#pragma unroll
    for (int dt = 0; dt < 2; ++dt)
#pragma unroll
      for (int i = 0; i < 16; ++i) o[dt][i] = 0.f;
    float m = -3.0e38f, l = 0.f;

    // staging slots (256 thr): K rows {rK,rK+32} x 8d; V key-pair {2aV,2aV+1} x 8d
    const int rK = tid >> 3, cK = tid & 7;
    const int aV = tid & 31, dV = (tid >> 5) * 8;

    float4 kA0, kA1, kB0, kB1, vA0, vA1, vB0, vB1;
#define LOADKV(kt)                                                        \
    {   const float* kpA = kh + (size_t)((kt) + rK) * DD + 8 * cK;       \
        const float* kpB = kpA + 32 * DD;                                 \
        const float* vpA = vh + (size_t)((kt) + 2 * aV) * DD + dV;       \
        const float* vpB = vpA + DD;                                      \
        kA0 = *(const float4*)kpA; kA1 = *(const float4*)(kpA + 4);      \
        kB0 = *(const float4*)kpB; kB1 = *(const float4*)(kpB + 4);      \
        vA0 = *(const float4*)vpA; vA1 = *(const float4*)(vpA + 4);      \
        vB0 = *(const float4*)vpB; vB1 = *(const float4*)(vpB + 4);      }

#define WRITEKV(Kp, Vp)                                                   \
    {   union { int i[4]; bf16x8 b; } kw;                                 \
        kw.i[0] = cvt_pk(kA0.x, kA0.y); kw.i[1] = cvt_pk(kA0.z, kA0.w);  \
        kw.i[2] = cvt_pk(kA1.x, kA1.y); kw.i[3] = cvt_pk(kA1.z, kA1.w);  \
        *(bf16x8*)((Kp) + swz(rK, 16 * cK)) = kw.b;                       \
        kw.i[0] = cvt_pk(kB0.x, kB0.y); kw.i[1] = cvt_pk(kB0.z, kB0.w);  \
        kw.i[2] = cvt_pk(kB1.x, kB1.y); kw.i[3] = cvt_pk(kB1.z, kB1.w);  \
        *(bf16x8*)((Kp) + swz(rK + 32, 16 * cK)) = kw.b;                  \
        float va[8] = {vA0.x, vA0.y, vA0.z, vA0.w, vA1.x, vA1.y, vA1.z, vA1.w}; \
        float vb[8] = {vB0.x, vB0.y, vB0.z, vB0.w, vB1.x, vB1.y, vB1.z, vB1.w}; \
        _Pragma("unroll")                                                 \
        for (int j = 0; j < 8; ++j)                                       \
            *(unsigned*)((Vp) + (dV + j) * 128 + ((4 * aV) ^ (j << 4)))  \
                = (unsigned)cvt_pk(va[j], vb[j]);                         }

    LOADKV(0)
    WRITEKV(smem, smem + 8192)
    __syncthreads();

    int boff = 0;
    for (int it = 0; it < NT; ++it) {
        const int kt = it * 64;
        const bool more = (it + 1 < NT);
        if (more) LOADKV(kt + 64)          // T14: issue early, write late
        char* Kb = smem + boff;
        char* Vb = Kb + 8192;

        // ---- QK^T (swapped): s[kb] = S^T[32kb+key][q], C-init = mask addend ----
        const float* mf = Mf + kt;
        f32x16 s0, s1;
#pragma unroll
        for (int g = 0; g < 4; ++g) {
            float4 m0 = *(const float4*)(mf + 8 * g + 4 * hi);        // kb=0
            float4 m1 = *(const float4*)(mf + 32 + 8 * g + 4 * hi);   // kb=1
            s0[4*g+0] = m0.x; s0[4*g+1] = m0.y; s0[4*g+2] = m0.z; s0[4*g+3] = m0.w;
            s1[4*g+0] = m1.x; s1[4*g+1] = m1.y; s1[4*g+2] = m1.z; s1[4*g+3] = m1.w;
        }
        __builtin_amdgcn_s_setprio(1);
#pragma unroll
        for (int dc = 0; dc < 4; ++dc) {
            bf16x8 k0 = *(const bf16x8*)(Kb + swz(l31,      32 * dc + 16 * hi));
            bf16x8 k1 = *(const bf16x8*)(Kb + swz(32 + l31, 32 * dc + 16 * hi));
            s0 = __builtin_amdgcn_mfma_f32_32x32x16_bf16(k0, qf[dc], s0, 0, 0, 0);
            s1 = __builtin_amdgcn_mfma_f32_32x32x16_bf16(k1, qf[dc], s1, 0, 0, 0);
        }
        __builtin_amdgcn_s_setprio(0);

        // ---- in-lane max tree + cross-half combine ----
        float t[16];
#pragma unroll
        for (int i = 0; i < 16; ++i) t[i] = fmaxf(s0[i], s1[i]);
#pragma unroll
        for (int stp = 8; stp >= 1; stp >>= 1)
#pragma unroll
            for (int i = 0; i < stp; ++i) t[i] = fmaxf(t[i], t[i + stp]);
        float pmax = xmax(t[0]);

        float mn = m;
        if (!__all(pmax <= m + THRL)) {       // T13 defer-rescale
            mn = fmaxf(m, pmax);
            float al = __builtin_amdgcn_exp2f(m - mn);
            l *= al;
#pragma unroll
            for (int dt = 0; dt < 2; ++dt)
#pragma unroll
              for (int i = 0; i < 16; ++i) o[dt][i] *= al;
            m = mn;
        }

        float p0[16], p1[16];
#pragma unroll
        for (int i = 0; i < 16; ++i) {
            p0[i] = __builtin_amdgcn_exp2f(s0[i] - mn);
            p1[i] = __builtin_amdgcn_exp2f(s1[i] - mn);
        }
        float u[16];
#pragma unroll
        for (int i = 0; i < 16; ++i) u[i] = p0[i] + p1[i];
#pragma unroll
        for (int stp = 8; stp >= 1; stp >>= 1)
#pragma unroll
            for (int i = 0; i < stp; ++i) u[i] += u[i + stp];
        l += xsum(u[0]);

        // ---- pack P -> bf16 pairs (keys (8g+4hi)..+3 per group g) ----
        unsigned pk[2][4][2];
#pragma unroll
        for (int g = 0; g < 4; ++g) {
            pk[0][g][0] = (unsigned)cvt_pk(p0[4*g+0], p0[4*g+1]);
            pk[0][g][1] = (unsigned)cvt_pk(p0[4*g+2], p0[4*g+3]);
            pk[1][g][0] = (unsigned)cvt_pk(p1[4*g+0], p1[4*g+1]);
            pk[1][g][1] = (unsigned)cvt_pk(p1[4*g+2], p1[4*g+3]);
        }

        if (more) {                        // stage next tile into other buffer
            char* Kn = smem + (boff ^ 16384);
            WRITEKV(Kn, Kn + 8192)
        }

        // ---- PV: O^T += V^T . P^T (P exchanged via permlane32_swap) ----
        __builtin_amdgcn_s_setprio(1);
#pragma unroll
        for (int kc = 0; kc < 4; ++kc) {
            const int kb = kc >> 1, kp = kc & 1;
            union { unsigned u[4]; bf16x8 b; } pu;
            unsigned lo0, hi0, lo1, hi1;
            plswap2(pk[kb][2*kp][0], pk[kb][2*kp+1][0], lo0, hi0, hi);
            plswap2(pk[kb][2*kp][1], pk[kb][2*kp+1][1], lo1, hi1, hi);
            pu.u[0] = lo0; pu.u[1] = lo1; pu.u[2] = hi0; pu.u[3] = hi1;
#pragma unroll
            for (int dt = 0; dt < 2; ++dt) {
                bf16x8 vf = *(const bf16x8*)(Vb + swz(32 * dt + l31, 32 * kc + 16 * hi));
                o[dt] = __builtin_amdgcn_mfma_f32_32x32x16_bf16(vf, pu.b, o[dt], 0, 0, 0);
            }
        }
        __builtin_amdgcn_s_setprio(0);

        __syncthreads();          // cur reads done + next buffer visible
        boff ^= 16384;
    }

    // ---- epilogue: O^T col q=l31, row d = (reg&3)+8*(reg>>2)+4*hi+32*dt ----
    const float invl = 1.0f / l;
    float* op = out + (size_t)h * SQ * DD + (size_t)qrow * DD;
#pragma unroll
    for (int dt = 0; dt < 2; ++dt)
#pragma unroll
      for (int g = 0; g < 4; ++g) {
        float4 r = { o[dt][4*g+0] * invl, o[dt][4*g+1] * invl,
                     o[dt][4*g+2] * invl, o[dt][4*g+3] * invl };
        *(float4*)(op + 32 * dt + 8 * g + 4 * hi) = r;
      }
}

extern "C" void kernel_launch(void* const* d_in, const int* in_sizes, int n_in,
                              void* d_out, int out_size, void* d_ws, size_t ws_size,
                              hipStream_t stream) {
    const float* q = (const float*)d_in[0];
    const float* k = (const float*)d_in[1];
    const float* v = (const float*)d_in[2];
    const int* masks = (const int*)d_in[3];
    float* out = (float*)d_out;
    attn_fwd<<<dim3(512), dim3(256), 0, stream>>>(q, k, v, masks, out);
}

// Round 5
// 62.565 us; speedup vs baseline: 2.0522x; 1.0013x over previous
//
#include <hip/hip_runtime.h>
#include <hip/hip_bf16.h>

// Flash attention fwd, swapped-QK^T 32x32x16 MFMA, in-register softmax.
// BH=32, S=2048, D=64, B=2 key-padding masks.
// Block = 256 thr (4 waves), wave = 32 q rows; grid 512 (2 blocks/CU).
// S^T = mfma(K, Q): lane owns q = lane&31; softmax in-lane + permlane32_swap.
// P in registers (cvt_pk bf16 + permlane32_swap) -> PV: O^T = mfma(V^T, P^T).
// LDS layout: FRAGMENT-LINEAR. K/V tiles stored as 8 chunks x 1024B; element
// e = hi*32+l31 of a chunk is lane e's 16B MFMA fragment, slot-permuted by
// off(c,e) = c*1024 + (e ^ ((c&3)*2 + (e>>5)))*16  -> frag reads are
// lane-linear (conflict-free), staging writes hit 8 distinct banks per
// 8-lane phase. (Round-4's [row][128B] + 8-row XOR was 4-way conflicted on
// 32-row fragment reads: SQ_LDS_BANK_CONFLICT 4.2M.)
// Mask staged once as log2e-scaled addend, used as MFMA C-init.
// K/V double-buffered (1 barrier/tile). All f32->bf16 via cvt_pk.
// T5 setprio around MFMA. T13 defer-rescale. T14 load-early/write-late. exp2.

#define SQ 2048
#define DD 64
#define NT 32   // 2048 / 64 KV tiles

typedef __attribute__((ext_vector_type(8)))  short bf16x8;
typedef __attribute__((ext_vector_type(16))) float f32x16;
typedef __attribute__((ext_vector_type(2)))  unsigned uint2v;

#define LOG2E  1.4426950408889634f
#define QSCALE (0.125f * LOG2E)
#define MASKV  (-4294967295.0f * LOG2E)   // MASK_NUM in log2 domain
#define THRL   (8.0f * LOG2E)             // defer-rescale threshold

__device__ __forceinline__ int cvt_pk(float lo, float hi) {
    int r;
    asm("v_cvt_pk_bf16_f32 %0, %1, %2" : "=v"(r) : "v"(lo), "v"(hi));
    return r;
}
// fragment-linear chunk addressing: chunk c (0..7), element e (0..63)
__device__ __forceinline__ int koff(int c, int e) {
    return c * 1024 + ((e ^ (((c & 3) << 1) | (e >> 5))) << 4);
}
// orientation-independent cross-half combines (swap(x,x) = both row-bcasts)
__device__ __forceinline__ float xmax(float x) {
#if __has_builtin(__builtin_amdgcn_permlane32_swap)
    union { float f; unsigned u; } a; a.f = x;
    uint2v r = __builtin_amdgcn_permlane32_swap(a.u, a.u, false, false);
    union { unsigned u; float f; } p0, p1; p0.u = r[0]; p1.u = r[1];
    return fmaxf(p0.f, p1.f);
#else
    return fmaxf(x, __shfl_xor(x, 32));
#endif
}
__device__ __forceinline__ float xsum(float x) {
#if __has_builtin(__builtin_amdgcn_permlane32_swap)
    union { float f; unsigned u; } a; a.f = x;
    uint2v r = __builtin_amdgcn_permlane32_swap(a.u, a.u, false, false);
    union { unsigned u; float f; } p0, p1; p0.u = r[0]; p1.u = r[1];
    return p0.f + p1.f;
#else
    return x + __shfl_xor(x, 32);
#endif
}
// PV B-operand words: a = pk[2kp] (keys 16kp+4hi..+3), b = pk[2kp+1] (+8).
// lo01: hi=0 own a, hi=1 partner b -> r[0]; hi23: hi=0 partner a, hi=1 own b -> r[1]
__device__ __forceinline__ void plswap2(unsigned a, unsigned b,
                                        unsigned& lo01, unsigned& hi23, int hi) {
#if __has_builtin(__builtin_amdgcn_permlane32_swap)
    uint2v r = __builtin_amdgcn_permlane32_swap(a, b, false, false);
    lo01 = r[0]; hi23 = r[1];
#else
    unsigned pa = (unsigned)__shfl_xor((int)a, 32);
    unsigned pb = (unsigned)__shfl_xor((int)b, 32);
    lo01 = hi ? pb : a;
    hi23 = hi ? b : pa;
#endif
}

__global__ __launch_bounds__(256, 2) void attn_fwd(
    const float* __restrict__ q, const float* __restrict__ k,
    const float* __restrict__ v, const int* __restrict__ masks,
    float* __restrict__ out)
{
    // buf0: K@0 V@8192 | buf1: K@16384 V@24576 | mask @32768 (8KB)
    __shared__ alignas(16) char smem[40960];
    float* Mf = (float*)(smem + 32768);

    const int x    = blockIdx.x;
    const int orig = (x & 7) * 64 + (x >> 3);  // bijective XCD swizzle (512=8*64)
    const int h    = orig >> 4;                // 4 heads/XCD -> K/V L2 reuse
    const int qb   = orig & 15;
    const int tid  = threadIdx.x;
    const int w    = tid >> 6;
    const int lane = tid & 63;
    const int l31  = lane & 31;
    const int hi   = lane >> 5;

    const float* __restrict__ qh = q + (size_t)h * SQ * DD;
    const float* __restrict__ kh = k + (size_t)h * SQ * DD;
    const float* __restrict__ vh = v + (size_t)h * SQ * DD;
    const int*   __restrict__ mrow = masks + (h & 1) * SQ;   // bh % 2

    // ---- stage mask addend table once (2048 floats) ----
    {
        int4 a = *(const int4*)(mrow + tid * 8);
        int4 b = *(const int4*)(mrow + tid * 8 + 4);
        float4 fa = { a.x ? MASKV : 0.f, a.y ? MASKV : 0.f,
                      a.z ? MASKV : 0.f, a.w ? MASKV : 0.f };
        float4 fb = { b.x ? MASKV : 0.f, b.y ? MASKV : 0.f,
                      b.z ? MASKV : 0.f, b.w ? MASKV : 0.f };
        *(float4*)(Mf + tid * 8)     = fa;
        *(float4*)(Mf + tid * 8 + 4) = fb;
    }

    // ---- Q fragments (B-operand: col=q=l31, k=d chunk), log2e*0.125 scale ----
    const int qrow = qb * 128 + w * 32 + l31;
    bf16x8 qf[4];
#pragma unroll
    for (int dc = 0; dc < 4; ++dc) {
        const float* p = qh + (size_t)qrow * DD + dc * 16 + hi * 8;
        float4 a = *(const float4*)p;
        float4 b = *(const float4*)(p + 4);
        union { int i[4]; bf16x8 v; } f;
        f.i[0] = cvt_pk(a.x * QSCALE, a.y * QSCALE);
        f.i[1] = cvt_pk(a.z * QSCALE, a.w * QSCALE);
        f.i[2] = cvt_pk(b.x * QSCALE, b.y * QSCALE);
        f.i[3] = cvt_pk(b.z * QSCALE, b.w * QSCALE);
        qf[dc] = f.v;
    }

    f32x16 o[2];
#pragma unroll
    for (int dt = 0; dt < 2; ++dt)
#pragma unroll
      for (int i = 0; i < 16; ++i) o[dt][i] = 0.f;
    float m = -3.0e38f, l = 0.f;

    // staging slots (256 thr): K rows {rK,rK+32} x 8d; V key-pair {2aV,2aV+1} x 8d
    const int rK = tid >> 3, cK = tid & 7;
    const int aV = tid & 31, dV = (tid >> 5) * 8;
    const int eK = ((cK & 1) << 5) | rK;          // K fragment element
    const int kA_off = koff(cK >> 1,       eK);
    const int kB_off = koff(4 + (cK >> 1), eK);

    float4 kA0, kA1, kB0, kB1, vA0, vA1, vB0, vB1;
#define LOADKV(kt)                                                        \
    {   const float* kpA = kh + (size_t)((kt) + rK) * DD + 8 * cK;       \
        const float* kpB = kpA + 32 * DD;                                 \
        const float* vpA = vh + (size_t)((kt) + 2 * aV) * DD + dV;       \
        const float* vpB = vpA + DD;                                      \
        kA0 = *(const float4*)kpA; kA1 = *(const float4*)(kpA + 4);      \
        kB0 = *(const float4*)kpB; kB1 = *(const float4*)(kpB + 4);      \
        vA0 = *(const float4*)vpA; vA1 = *(const float4*)(vpA + 4);      \
        vB0 = *(const float4*)vpB; vB1 = *(const float4*)(vpB + 4);      }

#define WRITEKV(Kp, Vp)                                                   \
    {   union { int i[4]; bf16x8 b; } kw;                                 \
        kw.i[0] = cvt_pk(kA0.x, kA0.y); kw.i[1] = cvt_pk(kA0.z, kA0.w);  \
        kw.i[2] = cvt_pk(kA1.x, kA1.y); kw.i[3] = cvt_pk(kA1.z, kA1.w);  \
        *(bf16x8*)((Kp) + kA_off) = kw.b;                                 \
        kw.i[0] = cvt_pk(kB0.x, kB0.y); kw.i[1] = cvt_pk(kB0.z, kB0.w);  \
        kw.i[2] = cvt_pk(kB1.x, kB1.y); kw.i[3] = cvt_pk(kB1.z, kB1.w);  \
        *(bf16x8*)((Kp) + kB_off) = kw.b;                                 \
        float va[8] = {vA0.x, vA0.y, vA0.z, vA0.w, vA1.x, vA1.y, vA1.z, vA1.w}; \
        float vb[8] = {vB0.x, vB0.y, vB0.z, vB0.w, vB1.x, vB1.y, vB1.z, vB1.w}; \
        _Pragma("unroll")                                                 \
        for (int j = 0; j < 8; ++j) {                                     \
            const int r_ = dV + j;                                        \
            const int cv_ = ((aV >> 3) << 1) | (r_ >> 5);                 \
            const int ev_ = (((aV >> 2) & 1) << 5) | (r_ & 31);           \
            *(unsigned*)((Vp) + koff(cv_, ev_) + 4 * (aV & 3))            \
                = (unsigned)cvt_pk(va[j], vb[j]);                         \
        }                                                                 }

    LOADKV(0)
    WRITEKV(smem, smem + 8192)
    __syncthreads();

    int boff = 0;
    for (int it = 0; it < NT; ++it) {
        const int kt = it * 64;
        const bool more = (it + 1 < NT);
        if (more) LOADKV(kt + 64)          // T14: issue early, write late
        char* Kb = smem + boff;
        char* Vb = Kb + 8192;

        // ---- QK^T (swapped): s[kb] = S^T[32kb+key][q], C-init = mask addend ----
        const float* mf = Mf + kt;
        f32x16 s0, s1;
#pragma unroll
        for (int g = 0; g < 4; ++g) {
            float4 m0 = *(const float4*)(mf + 8 * g + 4 * hi);        // kb=0
            float4 m1 = *(const float4*)(mf + 32 + 8 * g + 4 * hi);   // kb=1
            s0[4*g+0] = m0.x; s0[4*g+1] = m0.y; s0[4*g+2] = m0.z; s0[4*g+3] = m0.w;
            s1[4*g+0] = m1.x; s1[4*g+1] = m1.y; s1[4*g+2] = m1.z; s1[4*g+3] = m1.w;
        }
        __builtin_amdgcn_s_setprio(1);
#pragma unroll
        for (int dc = 0; dc < 4; ++dc) {
            bf16x8 k0 = *(const bf16x8*)(Kb + koff(dc,     lane));
            bf16x8 k1 = *(const bf16x8*)(Kb + koff(4 + dc, lane));
            s0 = __builtin_amdgcn_mfma_f32_32x32x16_bf16(k0, qf[dc], s0, 0, 0, 0);
            s1 = __builtin_amdgcn_mfma_f32_32x32x16_bf16(k1, qf[dc], s1, 0, 0, 0);
        }
        __builtin_amdgcn_s_setprio(0);

        // ---- in-lane max tree + cross-half combine ----
        float t[16];
#pragma unroll
        for (int i = 0; i < 16; ++i) t[i] = fmaxf(s0[i], s1[i]);
#pragma unroll
        for (int stp = 8; stp >= 1; stp >>= 1)
#pragma unroll
            for (int i = 0; i < stp; ++i) t[i] = fmaxf(t[i], t[i + stp]);
        float pmax = xmax(t[0]);

        float mn = m;
        if (!__all(pmax <= m + THRL)) {       // T13 defer-rescale
            mn = fmaxf(m, pmax);
            float al = __builtin_amdgcn_exp2f(m - mn);
            l *= al;
#pragma unroll
            for (int dt = 0; dt < 2; ++dt)
#pragma unroll
              for (int i = 0; i < 16; ++i) o[dt][i] *= al;
            m = mn;
        }

        float p0[16], p1[16];
#pragma unroll
        for (int i = 0; i < 16; ++i) {
            p0[i] = __builtin_amdgcn_exp2f(s0[i] - mn);
            p1[i] = __builtin_amdgcn_exp2f(s1[i] - mn);
        }
        float u[16];
#pragma unroll
        for (int i = 0; i < 16; ++i) u[i] = p0[i] + p1[i];
#pragma unroll
        for (int stp = 8; stp >= 1; stp >>= 1)
#pragma unroll
            for (int i = 0; i < stp; ++i) u[i] += u[i + stp];
        l += xsum(u[0]);

        // ---- pack P -> bf16 pairs (keys (8g+4hi)..+3 per group g) ----
        unsigned pk[2][4][2];
#pragma unroll
        for (int g = 0; g < 4; ++g) {
            pk[0][g][0] = (unsigned)cvt_pk(p0[4*g+0], p0[4*g+1]);
            pk[0][g][1] = (unsigned)cvt_pk(p0[4*g+2], p0[4*g+3]);
            pk[1][g][0] = (unsigned)cvt_pk(p1[4*g+0], p1[4*g+1]);
            pk[1][g][1] = (unsigned)cvt_pk(p1[4*g+2], p1[4*g+3]);
        }

        if (more) {                        // stage next tile into other buffer
            char* Kn = smem + (boff ^ 16384);
            WRITEKV(Kn, Kn + 8192)
        }

        // ---- PV: O^T += V^T . P^T (P exchanged via permlane32_swap) ----
        __builtin_amdgcn_s_setprio(1);
#pragma unroll
        for (int kc = 0; kc < 4; ++kc) {
            const int kb = kc >> 1, kp = kc & 1;
            union { unsigned u[4]; bf16x8 b; } pu;
            unsigned lo0, hi0, lo1, hi1;
            plswap2(pk[kb][2*kp][0], pk[kb][2*kp+1][0], lo0, hi0, hi);
            plswap2(pk[kb][2*kp][1], pk[kb][2*kp+1][1], lo1, hi1, hi);
            pu.u[0] = lo0; pu.u[1] = lo1; pu.u[2] = hi0; pu.u[3] = hi1;
#pragma unroll
            for (int dt = 0; dt < 2; ++dt) {
                bf16x8 vf = *(const bf16x8*)(Vb + koff(kc * 2 + dt, lane));
                o[dt] = __builtin_amdgcn_mfma_f32_32x32x16_bf16(vf, pu.b, o[dt], 0, 0, 0);
            }
        }
        __builtin_amdgcn_s_setprio(0);

        __syncthreads();          // cur reads done + next buffer visible
        boff ^= 16384;
    }

    // ---- epilogue: O^T col q=l31, row d = (reg&3)+8*(reg>>2)+4*hi+32*dt ----
    const float invl = 1.0f / l;
    float* op = out + (size_t)h * SQ * DD + (size_t)qrow * DD;
#pragma unroll
    for (int dt = 0; dt < 2; ++dt)
#pragma unroll
      for (int g = 0; g < 4; ++g) {
        float4 r = { o[dt][4*g+0] * invl, o[dt][4*g+1] * invl,
                     o[dt][4*g+2] * invl, o[dt][4*g+3] * invl };
        *(float4*)(op + 32 * dt + 8 * g + 4 * hi) = r;
      }
}

extern "C" void kernel_launch(void* const* d_in, const int* in_sizes, int n_in,
                              void* d_out, int out_size, void* d_ws, size_t ws_size,
                              hipStream_t stream) {
    const float* q = (const float*)d_in[0];
    const float* k = (const float*)d_in[1];
    const float* v = (const float*)d_in[2];
    const int* masks = (const int*)d_in[3];
    float* out = (float*)d_out;
    attn_fwd<<<dim3(512), dim3(256), 0, stream>>>(q, k, v, masks, out);
}